// Round 4
// baseline (956.864 us; speedup 1.0000x reference)
//
#include <hip/hip_runtime.h>
#include <hip/hip_bf16.h>
#include <cstdint>
#include <cstddef>

// Problem constants
#define BB 2
#define SS 2048
#define DD 4096
#define HH 32
#define HKV 8
#define HDIM 128
#define NQKV 6144   // H*HD + 2*HKV*HD

typedef __attribute__((ext_vector_type(8))) short bf16x8;
typedef __attribute__((ext_vector_type(4))) float f32x4;
typedef __attribute__((ext_vector_type(16))) float f32x16;

#define GLOAD_LDS16(g, l) __builtin_amdgcn_global_load_lds( \
    (const __attribute__((address_space(1))) void*)(g), \
    (__attribute__((address_space(3))) void*)(l), 16, 0, 0)

// ---------- cast fp32 -> bf16 (vectorized) ----------
__global__ void cast_bf16_kernel(const float* __restrict__ in,
                                 __hip_bfloat16* __restrict__ out, int n4) {
  int i = blockIdx.x * 256 + threadIdx.x;
  if (i >= n4) return;
  float4 v = ((const float4*)in)[i];
  union { __hip_bfloat16 h[4]; short4 s4; } u;
  u.h[0] = __float2bfloat16(v.x);
  u.h[1] = __float2bfloat16(v.y);
  u.h[2] = __float2bfloat16(v.z);
  u.h[3] = __float2bfloat16(v.w);
  ((short4*)out)[i] = u.s4;
}

// ---------- fused weight transposes: 4 matrices in one launch ----------
__global__ void transpose_cast4_kernel(const float* __restrict__ Wq,
                                       const float* __restrict__ Wk,
                                       const float* __restrict__ Wv,
                                       const float* __restrict__ Wo,
                                       __hip_bfloat16* __restrict__ WqkvT,
                                       __hip_bfloat16* __restrict__ WoT) {
  __shared__ float tile[32][33];
  int id = blockIdx.x;
  const float* W; __hip_bfloat16* WT; int C, bx, by;
  if (id < 16384)      { W = Wq; WT = WqkvT;                         C = 4096; int l = id;         bx = l & 127; by = l >> 7; }
  else if (id < 20480) { W = Wk; WT = WqkvT + (size_t)4096 * 4096;   C = 1024; int l = id - 16384; bx = l & 31;  by = l >> 5; }
  else if (id < 24576) { W = Wv; WT = WqkvT + (size_t)5120 * 4096;   C = 1024; int l = id - 20480; bx = l & 31;  by = l >> 5; }
  else                 { W = Wo; WT = WoT;                           C = 4096; int l = id - 24576; bx = l & 127; by = l >> 7; }
  const int R = 4096;
  int c0 = bx * 32, r0 = by * 32;
  int tx = threadIdx.x, ty = threadIdx.y;  // 32 x 8
#pragma unroll
  for (int i = 0; i < 32; i += 8)
    tile[ty + i][tx] = W[(size_t)(r0 + ty + i) * C + c0 + tx];
  __syncthreads();
#pragma unroll
  for (int i = 0; i < 32; i += 8)
    WT[(size_t)(c0 + ty + i) * R + r0 + tx] = __float2bfloat16(tile[tx][ty + i]);
}

// ---------- V part of QKV -> VT [b][hkv][hd][s] (bf16 transpose) ----------
__global__ void vt_kernel(const __hip_bfloat16* __restrict__ QKV,
                          __hip_bfloat16* __restrict__ VT) {
  __shared__ __hip_bfloat16 tile[32][33];
  int c0 = blockIdx.x * 32;  // col within V part [0,1024)
  int r0 = blockIdx.y * 32;  // row within B*S [0,4096)
  int tx = threadIdx.x, ty = threadIdx.y;  // 32 x 8
#pragma unroll
  for (int i = 0; i < 32; i += 8)
    tile[ty + i][tx] = QKV[(size_t)(r0 + ty + i) * NQKV + 5120 + c0 + tx];
  __syncthreads();
#pragma unroll
  for (int i = 0; i < 32; i += 8) {
    int r = r0 + tx;          // b*S + s
    int c = c0 + ty + i;      // hkv*128 + hd
    VT[((size_t)(r >> 11) * 1024 + c) * SS + (r & 2047)] = tile[tx][ty + i];
  }
}

// ---------- NeoX RoPE in place on Q and K of QKV ----------
__global__ void rope_kernel(__hip_bfloat16* __restrict__ QKV,
                            const int* __restrict__ pos_ids) {
  int r = blockIdx.x;  // b*S + s
  float fpos = (float)pos_ids[r];
  __hip_bfloat16* row = QKV + (size_t)r * NQKV;
  for (int p = threadIdx.x; p < 2560; p += 256) {
    int base, i;
    if (p < 2048) { base = (p >> 6) * HDIM; i = p & 63; }               // Q heads
    else { int q = p - 2048; base = DD + (q >> 6) * HDIM; i = q & 63; } // K heads
    float inv = exp2f(-(float)i * 0.20762050593046015f);  // 10000^(-i/64)
    float f = fpos * inv;
    float c = cosf(f), s = sinf(f);
    float x1 = __bfloat162float(row[base + i]);
    float x2 = __bfloat162float(row[base + i + 64]);
    row[base + i]      = __float2bfloat16(x1 * c - x2 * s);
    row[base + i + 64] = __float2bfloat16(x2 * c + x1 * s);
  }
}

// ---------- GEMM: C(M,N) = A(M,K) * BT(N,K)^T, bf16 in, bf16/fp32 out ----------
// 128x128 tile, BK=64, 32x32x16 MFMA (4060 FLOP/cyc ceiling vs 3378 for 16x16),
// half the barrier count of BK=32. LDS XOR-swizzled via global_load_lds SOURCE
// address (dest must stay wave-linear): chunk cl at row r holds cg = cl^(r&7).
// Frag-read granule-group = ((ks*2+lh)^(m&7))%8 -> 8 lanes/group = b128 floor.
template <int OUTF32>
__global__ __launch_bounds__(256) void gemm_bt_kernel(const __hip_bfloat16* __restrict__ A,
                                                      const __hip_bfloat16* __restrict__ BT,
                                                      void* __restrict__ Cout,
                                                      int M, int N, int K) {
  __shared__ alignas(16) __hip_bfloat16 As[128 * 64];
  __shared__ alignas(16) __hip_bfloat16 Bs[128 * 64];
  int bn = blockIdx.x, bm = blockIdx.y;
  int tid = threadIdx.x, wave = tid >> 6, lane = tid & 63;
  int lm = lane & 31, lh = lane >> 5;  // m/n index, k-half
  int wm = (wave >> 1) * 64, wn = (wave & 1) * 64;
  int row0 = bm * 128, col0 = bn * 128;
  f32x16 acc[2][2] = {};
  for (int k0 = 0; k0 < K; k0 += 64) {
    __syncthreads();  // protect LDS from previous iteration's readers
#pragma unroll
    for (int i = 0; i < 4; ++i) {
      int c = tid + i * 256;            // chunk id [0,1024), 16B each
      int r = c >> 3, cl = c & 7;
      int cg = cl ^ (r & 7);            // source-side XOR swizzle
      GLOAD_LDS16(A + (size_t)(row0 + r) * K + k0 + cg * 8, As + (size_t)c * 8);
      GLOAD_LDS16(BT + (size_t)(col0 + r) * K + k0 + cg * 8, Bs + (size_t)c * 8);
    }
    __syncthreads();
#pragma unroll
    for (int ks = 0; ks < 4; ++ks) {
      bf16x8 af[2], bfb[2];
#pragma unroll
      for (int mt = 0; mt < 2; ++mt) {
        int cl = (ks * 2 + lh) ^ (lm & 7);
        af[mt] = *(const bf16x8*)(As + (wm + mt * 32 + lm) * 64 + cl * 8);
      }
#pragma unroll
      for (int nt = 0; nt < 2; ++nt) {
        int cl = (ks * 2 + lh) ^ (lm & 7);
        bfb[nt] = *(const bf16x8*)(Bs + (wn + nt * 32 + lm) * 64 + cl * 8);
      }
#pragma unroll
      for (int mt = 0; mt < 2; ++mt)
#pragma unroll
        for (int nt = 0; nt < 2; ++nt)
          acc[mt][nt] = __builtin_amdgcn_mfma_f32_32x32x16_bf16(af[mt], bfb[nt], acc[mt][nt], 0, 0, 0);
    }
  }
  // epilogue: 32x32 C/D layout (m74/m101): col=lane&31, row=(r&3)+8*(r>>2)+4*(lane>>5)
#pragma unroll
  for (int mt = 0; mt < 2; ++mt)
#pragma unroll
    for (int nt = 0; nt < 2; ++nt)
#pragma unroll
      for (int r = 0; r < 16; ++r) {
        int row = row0 + wm + mt * 32 + (r & 3) + 8 * (r >> 2) + 4 * lh;
        int col = col0 + wn + nt * 32 + lm;
        if (OUTF32) ((float*)Cout)[(size_t)row * N + col] = acc[mt][nt][r];
        else ((__hip_bfloat16*)Cout)[(size_t)row * N + col] = __float2bfloat16(acc[mt][nt][r]);
      }
}

// ---------- Flash attention v3: GQA causal, online softmax ----------
// grid (16, H, B) = 1024 blocks, block 256 (4 waves). Each block does TWO
// q-tiles of 64 rows (qt = bx and 31-bx): 33 uniform kv-iters/block. Wave w
// owns q rows [qt*64 + w*16, +16). kv-tile 64. LDS = 40 KB -> 4 blocks/CU.
// K/V/P all XOR-swizzled at 16B-chunk granularity; no padding (global_load_lds
// dest must be wave-linear, so swizzle rides the SOURCE address).
__global__ __launch_bounds__(256, 4) void attn_kernel(const __hip_bfloat16* __restrict__ QKV,
                                                      const __hip_bfloat16* __restrict__ VT,
                                                      __hip_bfloat16* __restrict__ Ctx) {
  __shared__ alignas(16) __hip_bfloat16 Ks[64 * 128];   // (kv, hd): chunk(r,cl) = global cl^(r&15)
  __shared__ alignas(16) __hip_bfloat16 Vs[128 * 64];   // (hd, kv): chunk(r,cl) = global cl^(r&7)
  __shared__ alignas(16) __hip_bfloat16 Ps[4][16 * 64]; // per-wave P (q, kv), chunk-swizzled
  int h = blockIdx.y, b = blockIdx.z;
  int hkv = h >> 2;  // G = 4
  int tid = threadIdx.x, wave = tid >> 6, lane = tid & 63;
  int lr = lane & 15, lq = lane >> 4;
  const __hip_bfloat16* Kbase = QKV + (size_t)b * SS * NQKV + DD + hkv * HDIM;
  const __hip_bfloat16* Vbase = VT + (size_t)(b * HKV + hkv) * HDIM * SS;
  const float scale = 0.08838834764831845f;  // 1/sqrt(128)

  for (int half = 0; half < 2; ++half) {
    int qt = half ? (31 - blockIdx.x) : blockIdx.x;
    int q0 = qt * 64 + wave * 16;  // this wave's q rows

    // Q fragments (A-operand: m=lr, k=lq*8+j)
    const __hip_bfloat16* qrow = QKV + (size_t)(b * SS + q0 + lr) * NQKV + h * HDIM;
    bf16x8 qfrag[4];
#pragma unroll
    for (int ks = 0; ks < 4; ++ks) qfrag[ks] = *(const bf16x8*)(qrow + ks * 32 + lq * 8);

    f32x4 accO[8] = {};
    float m_r[4] = {-1e30f, -1e30f, -1e30f, -1e30f};
    float l_r[4] = {0.f, 0.f, 0.f, 0.f};

    int kv_end = qt * 64 + 64;
    for (int kv0 = 0; kv0 < kv_end; kv0 += 64) {
      __syncthreads();  // protect Ks/Vs from previous iteration's readers
      // K tile 64x128 (1024 chunks), source-side XOR swizzle
#pragma unroll
      for (int i = 0; i < 4; ++i) {
        int c = tid + i * 256;
        int r = c >> 4, cl = c & 15, cg = cl ^ (r & 15);
        GLOAD_LDS16(Kbase + (size_t)(kv0 + r) * NQKV + cg * 8, Ks + (size_t)c * 8);
      }
      // V tile 128x64 (1024 chunks)
#pragma unroll
      for (int i = 0; i < 4; ++i) {
        int c = tid + i * 256;
        int r = c >> 3, cl = c & 7, cg = cl ^ (r & 7);
        GLOAD_LDS16(Vbase + (size_t)r * SS + kv0 + cg * 8, Vs + (size_t)c * 8);
      }
      __syncthreads();

      // scores: Q(16x128) x K^T(64x128) -> sc[4] tiles of 16x16
      f32x4 sc[4] = {};
#pragma unroll
      for (int nt = 0; nt < 4; ++nt)
#pragma unroll
        for (int ks = 0; ks < 4; ++ks) {
          int cl = (ks * 4 + lq) ^ lr;  // swizzled chunk
          bf16x8 kf = *(const bf16x8*)(Ks + ((nt * 16 + lr) * 16 + cl) * 8);
          sc[nt] = __builtin_amdgcn_mfma_f32_16x16x32_bf16(qfrag[ks], kf, sc[nt], 0, 0, 0);
        }

      // scale + causal mask (only the final iteration touches the diagonal)
      if (kv0 + 64 > qt * 64) {
#pragma unroll
        for (int nt = 0; nt < 4; ++nt)
#pragma unroll
          for (int r = 0; r < 4; ++r) {
            float v = sc[nt][r] * scale;
            int qp = q0 + lq * 4 + r;
            int kp = kv0 + nt * 16 + lr;
            sc[nt][r] = (kp > qp) ? -1e30f : v;
          }
      } else {
#pragma unroll
        for (int nt = 0; nt < 4; ++nt)
#pragma unroll
          for (int r = 0; r < 4; ++r) sc[nt][r] *= scale;
      }

      // online softmax (row = lq*4+r; reduce over lr via shfl within 16 lanes)
      float alpha[4];
#pragma unroll
      for (int r = 0; r < 4; ++r) {
        float mx = fmaxf(fmaxf(sc[0][r], sc[1][r]), fmaxf(sc[2][r], sc[3][r]));
#pragma unroll
        for (int d = 1; d < 16; d <<= 1) mx = fmaxf(mx, __shfl_xor(mx, d));
        float mnew = fmaxf(m_r[r], mx);
        alpha[r] = __expf(m_r[r] - mnew);
        m_r[r] = mnew;
      }
#pragma unroll
      for (int nt = 0; nt < 4; ++nt)
#pragma unroll
        for (int r = 0; r < 4; ++r) sc[nt][r] = __expf(sc[nt][r] - m_r[r]);
#pragma unroll
      for (int r = 0; r < 4; ++r) {
        float sm = (sc[0][r] + sc[1][r]) + (sc[2][r] + sc[3][r]);
#pragma unroll
        for (int d = 1; d < 16; d <<= 1) sm += __shfl_xor(sm, d);
        l_r[r] = l_r[r] * alpha[r] + sm;
      }
#pragma unroll
      for (int t = 0; t < 8; ++t)
#pragma unroll
        for (int r = 0; r < 4; ++r) accO[t][r] *= alpha[r];

      // P: C-layout -> per-wave LDS (chunk-swizzled) -> A-operand layout.
      // No barrier: Ps[wave] is wave-private; compiler orders DS ops.
      __hip_bfloat16* P = Ps[wave];
#pragma unroll
      for (int nt = 0; nt < 4; ++nt)
#pragma unroll
        for (int r = 0; r < 4; ++r) {
          int row = lq * 4 + r;
          int cs = (nt * 2 + (lr >> 3)) ^ (row & 7);
          P[row * 64 + cs * 8 + (lr & 7)] = __float2bfloat16(sc[nt][r]);
        }

      // PV: P(16x64) x V^T(128x64) -> accO[8]
#pragma unroll
      for (int ks2 = 0; ks2 < 2; ++ks2) {
        bf16x8 pf = *(const bf16x8*)(P + lr * 64 + ((ks2 * 4 + lq) ^ (lr & 7)) * 8);
#pragma unroll
        for (int t = 0; t < 8; ++t) {
          int cl = (ks2 * 4 + lq) ^ (lr & 7);  // Vs swizzled chunk (row&7 = lr&7)
          bf16x8 vf = *(const bf16x8*)(Vs + ((t * 16 + lr) * 8 + cl) * 8);
          accO[t] = __builtin_amdgcn_mfma_f32_16x16x32_bf16(pf, vf, accO[t], 0, 0, 0);
        }
      }
    }

    // epilogue: O /= l, store ctx bf16 at [b*S+q, h*128+hd]
#pragma unroll
    for (int t = 0; t < 8; ++t)
#pragma unroll
      for (int r = 0; r < 4; ++r) {
        float o = accO[t][r] / l_r[r];
        int row = q0 + lq * 4 + r;
        int col = h * HDIM + t * 16 + lr;
        Ctx[(size_t)(b * SS + row) * (HH * HDIM) + col] = __float2bfloat16(o);
      }
  }
}

extern "C" void kernel_launch(void* const* d_in, const int* in_sizes, int n_in,
                              void* d_out, int out_size, void* d_ws, size_t ws_size,
                              hipStream_t stream) {
  const float* X  = (const float*)d_in[0];
  const int* pos  = (const int*)d_in[1];
  // d_in[2] attention_mask: all ones -> causal mask only
  const float* Wq = (const float*)d_in[3];
  const float* Wk = (const float*)d_in[4];
  const float* Wv = (const float*)d_in[5];
  const float* Wo = (const float*)d_in[6];
  float* out = (float*)d_out;

  char* ws = (char*)d_ws;
  // Layout (bytes):
  //   Xb   @ 0          32 MiB  (dead after QKV gemm; Ctx aliases it)
  //   WqkvT@ 33554432   48 MiB
  //   WoT  @ 83886080   32 MiB
  //   QKV  @ 117440512  48 MiB
  //   VT   @ 167772160   8 MiB
  __hip_bfloat16* Xb    = (__hip_bfloat16*)(ws);
  __hip_bfloat16* Ctx   = (__hip_bfloat16*)(ws);  // alias of Xb (disjoint lifetime)
  __hip_bfloat16* WqkvT = (__hip_bfloat16*)(ws + 33554432);
  __hip_bfloat16* WoT   = (__hip_bfloat16*)(ws + 83886080);
  __hip_bfloat16* QKV   = (__hip_bfloat16*)(ws + 117440512);
  __hip_bfloat16* VT    = (__hip_bfloat16*)(ws + 167772160);

  const int n4 = (BB * SS * DD) / 4;
  cast_bf16_kernel<<<dim3(n4 / 256), dim3(256), 0, stream>>>(X, Xb, n4);

  transpose_cast4_kernel<<<dim3(40960), dim3(32, 8), 0, stream>>>(Wq, Wk, Wv, Wo, WqkvT, WoT);

  // QKV = Xb @ WqkvT^T  (M=4096, N=6144, K=4096)
  gemm_bt_kernel<0><<<dim3(6144 / 128, 4096 / 128), dim3(256), 0, stream>>>(Xb, WqkvT, QKV, 4096, 6144, 4096);

  rope_kernel<<<dim3(BB * SS), dim3(256), 0, stream>>>(QKV, pos);
  vt_kernel<<<dim3(1024 / 32, 4096 / 32), dim3(32, 8), 0, stream>>>(QKV, VT);

  // Flash attention: folded causal schedule, 1024 blocks, uniform work
  attn_kernel<<<dim3(SS / 128, HH, BB), dim3(256), 0, stream>>>(QKV, VT, Ctx);

  // out = Ctx @ WoT^T  (M=4096, N=4096, K=4096), fp32 out
  gemm_bt_kernel<1><<<dim3(4096 / 128, 4096 / 128), dim3(256), 0, stream>>>(Ctx, WoT, out, 4096, 4096, 4096);
}

// Round 5
// 857.982 us; speedup vs baseline: 1.1152x; 1.1152x over previous
//
#include <hip/hip_runtime.h>
#include <hip/hip_bf16.h>
#include <cstdint>
#include <cstddef>

// Problem constants
#define BB 2
#define SS 2048
#define DD 4096
#define HH 32
#define HKV 8
#define HDIM 128
#define NQKV 6144   // H*HD + 2*HKV*HD

typedef __attribute__((ext_vector_type(8))) short bf16x8;
typedef __attribute__((ext_vector_type(4))) float f32x4;
typedef __attribute__((ext_vector_type(16))) float f32x16;

#define GLOAD_LDS16(g, l) __builtin_amdgcn_global_load_lds( \
    (const __attribute__((address_space(1))) void*)(g), \
    (__attribute__((address_space(3))) void*)(l), 16, 0, 0)

// ---------- cast fp32 -> bf16 (vectorized) ----------
__global__ void cast_bf16_kernel(const float* __restrict__ in,
                                 __hip_bfloat16* __restrict__ out, int n4) {
  int i = blockIdx.x * 256 + threadIdx.x;
  if (i >= n4) return;
  float4 v = ((const float4*)in)[i];
  union { __hip_bfloat16 h[4]; short4 s4; } u;
  u.h[0] = __float2bfloat16(v.x);
  u.h[1] = __float2bfloat16(v.y);
  u.h[2] = __float2bfloat16(v.z);
  u.h[3] = __float2bfloat16(v.w);
  ((short4*)out)[i] = u.s4;
}

// ---------- fused weight transposes: 4 matrices in one launch ----------
__global__ void transpose_cast4_kernel(const float* __restrict__ Wq,
                                       const float* __restrict__ Wk,
                                       const float* __restrict__ Wv,
                                       const float* __restrict__ Wo,
                                       __hip_bfloat16* __restrict__ WqkvT,
                                       __hip_bfloat16* __restrict__ WoT) {
  __shared__ float tile[32][33];
  int id = blockIdx.x;
  const float* W; __hip_bfloat16* WT; int C, bx, by;
  if (id < 16384)      { W = Wq; WT = WqkvT;                         C = 4096; int l = id;         bx = l & 127; by = l >> 7; }
  else if (id < 20480) { W = Wk; WT = WqkvT + (size_t)4096 * 4096;   C = 1024; int l = id - 16384; bx = l & 31;  by = l >> 5; }
  else if (id < 24576) { W = Wv; WT = WqkvT + (size_t)5120 * 4096;   C = 1024; int l = id - 20480; bx = l & 31;  by = l >> 5; }
  else                 { W = Wo; WT = WoT;                           C = 4096; int l = id - 24576; bx = l & 127; by = l >> 7; }
  const int R = 4096;
  int c0 = bx * 32, r0 = by * 32;
  int tx = threadIdx.x, ty = threadIdx.y;  // 32 x 8
#pragma unroll
  for (int i = 0; i < 32; i += 8)
    tile[ty + i][tx] = W[(size_t)(r0 + ty + i) * C + c0 + tx];
  __syncthreads();
#pragma unroll
  for (int i = 0; i < 32; i += 8)
    WT[(size_t)(c0 + ty + i) * R + r0 + tx] = __float2bfloat16(tile[tx][ty + i]);
}

// ---------- V part of QKV -> VT [b][hkv][hd][s] (bf16 transpose) ----------
__global__ void vt_kernel(const __hip_bfloat16* __restrict__ QKV,
                          __hip_bfloat16* __restrict__ VT) {
  __shared__ __hip_bfloat16 tile[32][33];
  int c0 = blockIdx.x * 32;  // col within V part [0,1024)
  int r0 = blockIdx.y * 32;  // row within B*S [0,4096)
  int tx = threadIdx.x, ty = threadIdx.y;  // 32 x 8
#pragma unroll
  for (int i = 0; i < 32; i += 8)
    tile[ty + i][tx] = QKV[(size_t)(r0 + ty + i) * NQKV + 5120 + c0 + tx];
  __syncthreads();
#pragma unroll
  for (int i = 0; i < 32; i += 8) {
    int r = r0 + tx;          // b*S + s
    int c = c0 + ty + i;      // hkv*128 + hd
    VT[((size_t)(r >> 11) * 1024 + c) * SS + (r & 2047)] = tile[tx][ty + i];
  }
}

// ---------- NeoX RoPE in place on Q and K of QKV ----------
__global__ void rope_kernel(__hip_bfloat16* __restrict__ QKV,
                            const int* __restrict__ pos_ids) {
  int r = blockIdx.x;  // b*S + s
  float fpos = (float)pos_ids[r];
  __hip_bfloat16* row = QKV + (size_t)r * NQKV;
  for (int p = threadIdx.x; p < 2560; p += 256) {
    int base, i;
    if (p < 2048) { base = (p >> 6) * HDIM; i = p & 63; }               // Q heads
    else { int q = p - 2048; base = DD + (q >> 6) * HDIM; i = q & 63; } // K heads
    float inv = exp2f(-(float)i * 0.20762050593046015f);  // 10000^(-i/64)
    float f = fpos * inv;
    float c = cosf(f), s = sinf(f);
    float x1 = __bfloat162float(row[base + i]);
    float x2 = __bfloat162float(row[base + i + 64]);
    row[base + i]      = __float2bfloat16(x1 * c - x2 * s);
    row[base + i + 64] = __float2bfloat16(x2 * c + x1 * s);
  }
}

// ---------- GEMM: C(M,N) = A(M,K) * BT(N,K)^T, bf16 in, bf16/fp32 out ----------
// 128x128 tile, BK=64, 32x32x16 MFMA, XOR-swizzled LDS via global_load_lds
// SOURCE address (dest must stay wave-linear): chunk cl at row r holds cg=cl^(r&7).
template <int OUTF32>
__global__ __launch_bounds__(256) void gemm_bt_kernel(const __hip_bfloat16* __restrict__ A,
                                                      const __hip_bfloat16* __restrict__ BT,
                                                      void* __restrict__ Cout,
                                                      int M, int N, int K) {
  __shared__ alignas(16) __hip_bfloat16 As[128 * 64];
  __shared__ alignas(16) __hip_bfloat16 Bs[128 * 64];
  int bn = blockIdx.x, bm = blockIdx.y;
  int tid = threadIdx.x, wave = tid >> 6, lane = tid & 63;
  int lm = lane & 31, lh = lane >> 5;  // m/n index, k-half
  int wm = (wave >> 1) * 64, wn = (wave & 1) * 64;
  int row0 = bm * 128, col0 = bn * 128;
  f32x16 acc[2][2] = {};
  for (int k0 = 0; k0 < K; k0 += 64) {
    __syncthreads();  // protect LDS from previous iteration's readers
#pragma unroll
    for (int i = 0; i < 4; ++i) {
      int c = tid + i * 256;            // chunk id [0,1024), 16B each
      int r = c >> 3, cl = c & 7;
      int cg = cl ^ (r & 7);            // source-side XOR swizzle
      GLOAD_LDS16(A + (size_t)(row0 + r) * K + k0 + cg * 8, As + (size_t)c * 8);
      GLOAD_LDS16(BT + (size_t)(col0 + r) * K + k0 + cg * 8, Bs + (size_t)c * 8);
    }
    __syncthreads();
#pragma unroll
    for (int ks = 0; ks < 4; ++ks) {
      bf16x8 af[2], bfb[2];
#pragma unroll
      for (int mt = 0; mt < 2; ++mt) {
        int cl = (ks * 2 + lh) ^ (lm & 7);
        af[mt] = *(const bf16x8*)(As + (wm + mt * 32 + lm) * 64 + cl * 8);
      }
#pragma unroll
      for (int nt = 0; nt < 2; ++nt) {
        int cl = (ks * 2 + lh) ^ (lm & 7);
        bfb[nt] = *(const bf16x8*)(Bs + (wn + nt * 32 + lm) * 64 + cl * 8);
      }
#pragma unroll
      for (int mt = 0; mt < 2; ++mt)
#pragma unroll
        for (int nt = 0; nt < 2; ++nt)
          acc[mt][nt] = __builtin_amdgcn_mfma_f32_32x32x16_bf16(af[mt], bfb[nt], acc[mt][nt], 0, 0, 0);
    }
  }
  // epilogue: 32x32 C/D layout (m74/m101): col=lane&31, row=(r&3)+8*(r>>2)+4*(lane>>5)
#pragma unroll
  for (int mt = 0; mt < 2; ++mt)
#pragma unroll
    for (int nt = 0; nt < 2; ++nt)
#pragma unroll
      for (int r = 0; r < 16; ++r) {
        int row = row0 + wm + mt * 32 + (r & 3) + 8 * (r >> 2) + 4 * lh;
        int col = col0 + wn + nt * 32 + lm;
        if (OUTF32) ((float*)Cout)[(size_t)row * N + col] = acc[mt][nt][r];
        else ((__hip_bfloat16*)Cout)[(size_t)row * N + col] = __float2bfloat16(acc[mt][nt][r]);
      }
}

// ---------- Flash attention v5: GQA causal, online softmax ----------
// grid (64 hb, 16 y), qt = 15 - y: LONGEST-FIRST unfolded schedule. All
// co-resident blocks stream kv monotonically from 0 (L2/L3-friendly, the
// R1 regime: 78 MB fetch) and LPT dispatch keeps CUs packed despite causal
// imbalance. Block = 4 waves, q-tile 128 (wave = 32 rows), kv-tile 64.
// LDS 48 KB -> 3 blocks/CU. K/V/P XOR-swizzled at 16B-chunk granularity.
__global__ __launch_bounds__(256) void attn_kernel(const __hip_bfloat16* __restrict__ QKV,
                                                   const __hip_bfloat16* __restrict__ VT,
                                                   __hip_bfloat16* __restrict__ Ctx) {
  __shared__ alignas(16) __hip_bfloat16 Ks[64 * 128];   // (kv, hd): chunk(r,cl) = global cl^(r&15)
  __shared__ alignas(16) __hip_bfloat16 Vs[128 * 64];   // (hd, kv): chunk(r,cl) = global cl^(r&7)
  __shared__ alignas(16) __hip_bfloat16 Ps[4][32 * 64]; // per-wave P (q, kv), chunk-swizzled
  int hb = blockIdx.x;
  int h = hb & 31, b = hb >> 5;
  int qt = 15 - blockIdx.y;  // longest blocks dispatch first
  int hkv = h >> 2;          // G = 4
  int tid = threadIdx.x, wave = tid >> 6, lane = tid & 63;
  int lr = lane & 15, lq = lane >> 4;
  const __hip_bfloat16* Kbase = QKV + (size_t)b * SS * NQKV + DD + hkv * HDIM;
  const __hip_bfloat16* Vbase = VT + (size_t)(b * HKV + hkv) * HDIM * SS;
  const float scale = 0.08838834764831845f;  // 1/sqrt(128)

  int q0 = qt * 128 + wave * 32;  // this wave's first q row

  // Q fragments: 2 m-tiles x 4 k-steps (A-operand: m=lr, k=lq*8+j)
  bf16x8 qfrag[2][4];
#pragma unroll
  for (int mt = 0; mt < 2; ++mt) {
    const __hip_bfloat16* qrow = QKV + (size_t)(b * SS + q0 + mt * 16 + lr) * NQKV + h * HDIM;
#pragma unroll
    for (int ks = 0; ks < 4; ++ks) qfrag[mt][ks] = *(const bf16x8*)(qrow + ks * 32 + lq * 8);
  }

  f32x4 accO[2][8] = {};
  float m_r[2][4], l_r[2][4];
#pragma unroll
  for (int mt = 0; mt < 2; ++mt)
#pragma unroll
    for (int r = 0; r < 4; ++r) { m_r[mt][r] = -1e30f; l_r[mt][r] = 0.f; }

  int kv_end = qt * 128 + 128;
  for (int kv0 = 0; kv0 < kv_end; kv0 += 64) {
    __syncthreads();  // protect Ks/Vs from previous iteration's readers
    // K tile 64x128 (1024 chunks), source-side XOR swizzle
#pragma unroll
    for (int i = 0; i < 4; ++i) {
      int c = tid + i * 256;
      int r = c >> 4, cl = c & 15, cg = cl ^ (r & 15);
      GLOAD_LDS16(Kbase + (size_t)(kv0 + r) * NQKV + cg * 8, Ks + (size_t)c * 8);
    }
    // V tile 128x64 (1024 chunks)
#pragma unroll
    for (int i = 0; i < 4; ++i) {
      int c = tid + i * 256;
      int r = c >> 3, cl = c & 7, cg = cl ^ (r & 7);
      GLOAD_LDS16(Vbase + (size_t)r * SS + kv0 + cg * 8, Vs + (size_t)c * 8);
    }
    __syncthreads();

    // scores: Q(2x16x128) x K^T(64x128) -> sc[2][4] tiles of 16x16
    f32x4 sc[2][4] = {};
#pragma unroll
    for (int nt = 0; nt < 4; ++nt)
#pragma unroll
      for (int ks = 0; ks < 4; ++ks) {
        int cl = (ks * 4 + lq) ^ lr;  // swizzled chunk
        bf16x8 kf = *(const bf16x8*)(Ks + ((nt * 16 + lr) * 16 + cl) * 8);
#pragma unroll
        for (int mt = 0; mt < 2; ++mt)
          sc[mt][nt] = __builtin_amdgcn_mfma_f32_16x16x32_bf16(qfrag[mt][ks], kf, sc[mt][nt], 0, 0, 0);
      }

    // scale + causal mask (only the last two iterations touch the diagonal)
    if (kv0 + 64 > qt * 128) {
#pragma unroll
      for (int mt = 0; mt < 2; ++mt)
#pragma unroll
        for (int nt = 0; nt < 4; ++nt)
#pragma unroll
          for (int r = 0; r < 4; ++r) {
            float v = sc[mt][nt][r] * scale;
            int qp = q0 + mt * 16 + lq * 4 + r;
            int kp = kv0 + nt * 16 + lr;
            sc[mt][nt][r] = (kp > qp) ? -1e30f : v;
          }
    } else {
#pragma unroll
      for (int mt = 0; mt < 2; ++mt)
#pragma unroll
        for (int nt = 0; nt < 4; ++nt)
#pragma unroll
          for (int r = 0; r < 4; ++r) sc[mt][nt][r] *= scale;
    }

    // online softmax (row = lq*4+r within each m-tile; reduce over lr via shfl)
    float alpha[2][4];
#pragma unroll
    for (int mt = 0; mt < 2; ++mt)
#pragma unroll
      for (int r = 0; r < 4; ++r) {
        float mx = fmaxf(fmaxf(sc[mt][0][r], sc[mt][1][r]), fmaxf(sc[mt][2][r], sc[mt][3][r]));
#pragma unroll
        for (int d = 1; d < 16; d <<= 1) mx = fmaxf(mx, __shfl_xor(mx, d));
        float mnew = fmaxf(m_r[mt][r], mx);
        alpha[mt][r] = __expf(m_r[mt][r] - mnew);
        m_r[mt][r] = mnew;
      }
#pragma unroll
    for (int mt = 0; mt < 2; ++mt)
#pragma unroll
      for (int nt = 0; nt < 4; ++nt)
#pragma unroll
        for (int r = 0; r < 4; ++r) sc[mt][nt][r] = __expf(sc[mt][nt][r] - m_r[mt][r]);
#pragma unroll
    for (int mt = 0; mt < 2; ++mt)
#pragma unroll
      for (int r = 0; r < 4; ++r) {
        float sm = (sc[mt][0][r] + sc[mt][1][r]) + (sc[mt][2][r] + sc[mt][3][r]);
#pragma unroll
        for (int d = 1; d < 16; d <<= 1) sm += __shfl_xor(sm, d);
        l_r[mt][r] = l_r[mt][r] * alpha[mt][r] + sm;
      }
#pragma unroll
    for (int mt = 0; mt < 2; ++mt)
#pragma unroll
      for (int t = 0; t < 8; ++t)
#pragma unroll
        for (int r = 0; r < 4; ++r) accO[mt][t][r] *= alpha[mt][r];

    // P: C-layout -> per-wave LDS (chunk-swizzled) -> A-operand layout.
    // No barrier: Ps[wave] is wave-private; compiler orders DS ops.
    __hip_bfloat16* P = Ps[wave];
#pragma unroll
    for (int mt = 0; mt < 2; ++mt)
#pragma unroll
      for (int nt = 0; nt < 4; ++nt)
#pragma unroll
        for (int r = 0; r < 4; ++r) {
          int row = mt * 16 + lq * 4 + r;
          int cs = (nt * 2 + (lr >> 3)) ^ (row & 7);
          P[row * 64 + cs * 8 + (lr & 7)] = __float2bfloat16(sc[mt][nt][r]);
        }

    // PV: P(2x16x64) x V^T(128x64) -> accO[2][8]
#pragma unroll
    for (int ks2 = 0; ks2 < 2; ++ks2) {
      bf16x8 pf[2];
#pragma unroll
      for (int mt = 0; mt < 2; ++mt) {
        int row = mt * 16 + lr;
        pf[mt] = *(const bf16x8*)(P + row * 64 + (((ks2 * 4 + lq) ^ (row & 7))) * 8);
      }
#pragma unroll
      for (int t = 0; t < 8; ++t) {
        int cl = (ks2 * 4 + lq) ^ (lr & 7);  // Vs swizzled chunk (row&7 = lr&7)
        bf16x8 vf = *(const bf16x8*)(Vs + ((t * 16 + lr) * 8 + cl) * 8);
#pragma unroll
        for (int mt = 0; mt < 2; ++mt)
          accO[mt][t] = __builtin_amdgcn_mfma_f32_16x16x32_bf16(pf[mt], vf, accO[mt][t], 0, 0, 0);
      }
    }
  }

  // epilogue: O /= l, store ctx bf16 at [b*S+q, h*128+hd]
#pragma unroll
  for (int mt = 0; mt < 2; ++mt)
#pragma unroll
    for (int t = 0; t < 8; ++t)
#pragma unroll
      for (int r = 0; r < 4; ++r) {
        float o = accO[mt][t][r] / l_r[mt][r];
        int row = q0 + mt * 16 + lq * 4 + r;
        int col = h * HDIM + t * 16 + lr;
        Ctx[(size_t)(b * SS + row) * (HH * HDIM) + col] = __float2bfloat16(o);
      }
}

extern "C" void kernel_launch(void* const* d_in, const int* in_sizes, int n_in,
                              void* d_out, int out_size, void* d_ws, size_t ws_size,
                              hipStream_t stream) {
  const float* X  = (const float*)d_in[0];
  const int* pos  = (const int*)d_in[1];
  // d_in[2] attention_mask: all ones -> causal mask only
  const float* Wq = (const float*)d_in[3];
  const float* Wk = (const float*)d_in[4];
  const float* Wv = (const float*)d_in[5];
  const float* Wo = (const float*)d_in[6];
  float* out = (float*)d_out;

  char* ws = (char*)d_ws;
  // Layout (bytes):
  //   Xb   @ 0          32 MiB  (dead after QKV gemm; Ctx aliases it)
  //   WqkvT@ 33554432   48 MiB
  //   WoT  @ 83886080   32 MiB
  //   QKV  @ 117440512  48 MiB
  //   VT   @ 167772160   8 MiB
  __hip_bfloat16* Xb    = (__hip_bfloat16*)(ws);
  __hip_bfloat16* Ctx   = (__hip_bfloat16*)(ws);  // alias of Xb (disjoint lifetime)
  __hip_bfloat16* WqkvT = (__hip_bfloat16*)(ws + 33554432);
  __hip_bfloat16* WoT   = (__hip_bfloat16*)(ws + 83886080);
  __hip_bfloat16* QKV   = (__hip_bfloat16*)(ws + 117440512);
  __hip_bfloat16* VT    = (__hip_bfloat16*)(ws + 167772160);

  const int n4 = (BB * SS * DD) / 4;
  cast_bf16_kernel<<<dim3(n4 / 256), dim3(256), 0, stream>>>(X, Xb, n4);

  transpose_cast4_kernel<<<dim3(40960), dim3(32, 8), 0, stream>>>(Wq, Wk, Wv, Wo, WqkvT, WoT);

  // QKV = Xb @ WqkvT^T  (M=4096, N=6144, K=4096)
  gemm_bt_kernel<0><<<dim3(6144 / 128, 4096 / 128), dim3(256), 0, stream>>>(Xb, WqkvT, QKV, 4096, 6144, 4096);

  rope_kernel<<<dim3(BB * SS), dim3(256), 0, stream>>>(QKV, pos);
  vt_kernel<<<dim3(1024 / 32, 4096 / 32), dim3(32, 8), 0, stream>>>(QKV, VT);

  // Flash attention: unfolded longest-first schedule, 1024 blocks
  attn_kernel<<<dim3(64, 16), dim3(256), 0, stream>>>(QKV, VT, Ctx);

  // out = Ctx @ WoT^T  (M=4096, N=4096, K=4096), fp32 out
  gemm_bt_kernel<1><<<dim3(4096 / 128, 4096 / 128), dim3(256), 0, stream>>>(Ctx, WoT, out, 4096, 4096, 4096);
}